// Round 6
// baseline (126.817 us; speedup 1.0000x reference)
//
#include <hip/hip_runtime.h>

// out[c] = sum_i pre[idx_i][c] + dot(W[c,:], sum_i memb[idx_i]) + N*bias[c]
//
// Histogram formulation: counts[v] = multiplicity of row v (~39% of the 200k
// vocab rows are touched by 100k uniform draws); one monotone weighted scan
// reads each unique row ONCE from each table (~158 MB vs ~205 MB).
//
// R6 vs R5 (scan loop idiom PROVEN, untouched):
//  - counts packed as uint8 (Poisson lambda=0.5 -> max count << 255):
//    memset 800KB->200KB, hist atomics into packed words (no carry risk),
//    scan count-read 4x smaller
//  - finish matvec fused into scan via last-block ticket (R4's ticket was
//    correct; its matvec was serial/uncoalesced -- now each wave sweeps 64
//    channels with 64-lane f4 row reads + shuffle reduce): 4 -> 3 dispatches
//
// d_ws layout: [counts: ceil(V/4) u32][acc: NCOPY*512 f32][done: int]

typedef float f4 __attribute__((ext_vector_type(4)));

#define NCOPY 16

__global__ __launch_bounds__(256) void hist_kernel(
    const int* __restrict__ idx, unsigned int* __restrict__ countsW, int n)
{
    int i = blockIdx.x * blockDim.x + threadIdx.x;
    const int stride = gridDim.x * blockDim.x;
    for (; i < n; i += stride) {
        const int v = idx[i];
        atomicAdd(&countsW[v >> 2], 1u << ((v & 3) * 8));
    }
}

__global__ __launch_bounds__(256) void scan_finish_kernel(
    const unsigned char* __restrict__ cnt8,   // [V] packed counts
    const float* __restrict__ memb,   // [V,256]
    const float* __restrict__ pre,    // [V,256]
    float* __restrict__ acc,          // [NCOPY][512]
    int* __restrict__ done,
    const float* __restrict__ W,      // [256,256] row-major
    const float* __restrict__ bias,
    float* __restrict__ out,          // [256]
    int vocab, float nf, int nblocks)
{
    const int lane = threadIdx.x & 63;
    const int wid  = (blockIdx.x * blockDim.x + threadIdx.x) >> 6;
    const int tab  = wid & 1;                 // 0 -> memb, 1 -> pre
    const int base = (wid >> 1) * 64;         // 64-row window per wave pair

    f4 a4 = {0.f, 0.f, 0.f, 0.f};

    if (base < vocab) {
        int c = 0;
        if (base + lane < vocab) c = cnt8[base + lane];     // coalesced 64B
        const float cf = (float)c;
        unsigned long long m = __ballot(c != 0);

        const float* tbl = tab ? pre : memb;
        const f4* rows = reinterpret_cast<const f4*>(tbl) + (size_t)base * 64 + lane;

        // 4 surviving rows per iteration; wave-uniform control (ballot mask),
        // register-only deps -> 4x 1KB loads in flight. (Proven in R5.)
        while (m) {
            const int k0 = __ffsll(m) - 1; m &= m - 1;
            const float w0 = __shfl(cf, k0, 64);
            int k1 = k0, k2 = k0, k3 = k0;
            float w1 = 0.f, w2 = 0.f, w3 = 0.f;
            if (m) { k1 = __ffsll(m) - 1; m &= m - 1; w1 = __shfl(cf, k1, 64); }
            if (m) { k2 = __ffsll(m) - 1; m &= m - 1; w2 = __shfl(cf, k2, 64); }
            if (m) { k3 = __ffsll(m) - 1; m &= m - 1; w3 = __shfl(cf, k3, 64); }

            const f4 a0 = rows[(size_t)k0 * 64];
            const f4 a1 = rows[(size_t)k1 * 64];
            const f4 a2 = rows[(size_t)k2 * 64];
            const f4 a3 = rows[(size_t)k3 * 64];

            a4 += a0 * w0;
            a4 += a1 * w1;
            a4 += a2 * w2;
            a4 += a3 * w3;
        }
    }

    // Block reduction: lane l owns channels [4l,4l+4); even waves -> S,
    // odd waves -> P.
    __shared__ float sAcc[2][256];
    sAcc[0][threadIdx.x] = 0.f;
    sAcc[1][threadIdx.x] = 0.f;
    __syncthreads();

    const int ch = lane * 4;
    atomicAdd(&sAcc[tab][ch + 0], a4.x);
    atomicAdd(&sAcc[tab][ch + 1], a4.y);
    atomicAdd(&sAcc[tab][ch + 2], a4.z);
    atomicAdd(&sAcc[tab][ch + 3], a4.w);
    __syncthreads();

    float* myacc = acc + (size_t)(blockIdx.x & (NCOPY - 1)) * 512;
    atomicAdd(&myacc[threadIdx.x],       sAcc[0][threadIdx.x]);
    atomicAdd(&myacc[256 + threadIdx.x], sAcc[1][threadIdx.x]);

    // Last-block ticket -> fused finish.
    __shared__ int lastFlag;
    if (threadIdx.x == 0) {
        __threadfence();                       // release our acc atomics
        lastFlag = (atomicAdd(done, 1) == nblocks - 1);
    }
    __syncthreads();
    if (!lastFlag) return;
    __threadfence();                           // acquire all blocks' atomics

    const int t  = threadIdx.x;
    const int wv = t >> 6;

    __shared__ float sVec[256];
    __shared__ float pVec[256];
    float s_t = 0.f, p_t = 0.f;
    #pragma unroll
    for (int cp = 0; cp < NCOPY; ++cp) {
        s_t += acc[cp * 512 + t];
        p_t += acc[cp * 512 + 256 + t];
    }
    sVec[t] = s_t;
    pVec[t] = p_t;
    __syncthreads();

    // Coalesced matvec: wave wv sweeps channels [64*wv, 64*wv+64);
    // 64 lanes read one W row as f4 (1KB/instruction), shuffle-reduce.
    const f4* W4 = reinterpret_cast<const f4*>(W);
    const f4  sv = reinterpret_cast<const f4*>(sVec)[lane];
    for (int i = 0; i < 64; ++i) {
        const int c = wv * 64 + i;
        const f4 wr = W4[(size_t)c * 64 + lane];
        float v = wr.x * sv.x + wr.y * sv.y + wr.z * sv.z + wr.w * sv.w;
        #pragma unroll
        for (int off = 32; off > 0; off >>= 1)
            v += __shfl_xor(v, off, 64);
        if (lane == 0) out[c] = v + pVec[c] + nf * bias[c];
    }
}

// ---- Fallback path (ws too small): R1-style gather + separate finish ----
__global__ __launch_bounds__(256) void gather_sum_kernel(
    const int* __restrict__ idx,
    const float* __restrict__ memb,
    const float* __restrict__ pre,
    float* __restrict__ acc,
    int n)
{
    const int lane = threadIdx.x & 63;
    const int wave = threadIdx.x >> 6;
    const int globalWave = blockIdx.x * 4 + wave;
    const int totalWaves = gridDim.x * 4;

    f4 accS = {0.f,0.f,0.f,0.f};
    f4 accP = {0.f,0.f,0.f,0.f};

    for (int i = globalWave; i < n; i += totalWaves) {
        const int r = idx[i];
        const f4 a = reinterpret_cast<const f4*>(memb + (size_t)r * 256)[lane];
        const f4 b = reinterpret_cast<const f4*>(pre  + (size_t)r * 256)[lane];
        accS += a; accP += b;
    }

    __shared__ float sS[256];
    __shared__ float sP[256];
    sS[threadIdx.x] = 0.f;
    sP[threadIdx.x] = 0.f;
    __syncthreads();
    const int ch = lane * 4;
    atomicAdd(&sS[ch + 0], accS.x); atomicAdd(&sS[ch + 1], accS.y);
    atomicAdd(&sS[ch + 2], accS.z); atomicAdd(&sS[ch + 3], accS.w);
    atomicAdd(&sP[ch + 0], accP.x); atomicAdd(&sP[ch + 1], accP.y);
    atomicAdd(&sP[ch + 2], accP.z); atomicAdd(&sP[ch + 3], accP.w);
    __syncthreads();
    float* myacc = acc + (size_t)(blockIdx.x & (NCOPY - 1)) * 512;
    atomicAdd(&myacc[threadIdx.x],       sS[threadIdx.x]);
    atomicAdd(&myacc[256 + threadIdx.x], sP[threadIdx.x]);
}

__global__ __launch_bounds__(256) void finish_kernel(
    const float* __restrict__ acc,
    const float* __restrict__ W,
    const float* __restrict__ bias,
    float* __restrict__ out,
    float nf)
{
    const int c = blockIdx.x;
    const int t = threadIdx.x;

    float s_t = 0.f;
    #pragma unroll
    for (int cp = 0; cp < NCOPY; ++cp) s_t += acc[cp * 512 + t];

    float v = W[(size_t)c * 256 + t] * s_t;
    for (int off = 32; off > 0; off >>= 1)
        v += __shfl_down(v, off, 64);

    __shared__ float part[4];
    if ((t & 63) == 0) part[t >> 6] = v;
    __syncthreads();

    if (t == 0) {
        float p_c = 0.f;
        #pragma unroll
        for (int cp = 0; cp < NCOPY; ++cp) p_c += acc[cp * 512 + 256 + c];
        out[c] = (part[0] + part[1] + part[2] + part[3]) + p_c + nf * bias[c];
    }
}

extern "C" void kernel_launch(void* const* d_in, const int* in_sizes, int n_in,
                              void* d_out, int out_size, void* d_ws, size_t ws_size,
                              hipStream_t stream)
{
    const int*   idx  = (const int*)d_in[0];     // medicine_it      [N]
    const float* memb = (const float*)d_in[1];   // m_embeddings     [V,256]
    const float* pre  = (const float*)d_in[2];   // pretrained_weight[V,256]
    const float* W    = (const float*)d_in[3];   // W                [256,256]
    const float* bias = (const float*)d_in[4];   // bias             [256]
    float* out = (float*)d_out;

    const int n     = in_sizes[0];
    const int vocab = in_sizes[1] / 256;

    const size_t countsBytes = (size_t)((vocab + 3) / 4) * 4;   // u8, word-aligned
    const size_t accBytes    = (size_t)NCOPY * 512 * sizeof(float);

    if (ws_size >= countsBytes + accBytes + 64) {
        unsigned int* countsW = (unsigned int*)d_ws;
        float*        acc     = (float*)((char*)d_ws + countsBytes);
        int*          done    = (int*)((char*)d_ws + countsBytes + accBytes);

        hipMemsetAsync(d_ws, 0, countsBytes + accBytes + 64, stream);

        hist_kernel<<<400, 256, 0, stream>>>(idx, countsW, n);

        const int waves  = 2 * ((vocab + 63) / 64);          // 6250
        const int blocks = (waves + 3) / 4;                  // 1563
        scan_finish_kernel<<<blocks, 256, 0, stream>>>(
            (const unsigned char*)countsW, memb, pre, acc, done,
            W, bias, out, vocab, (float)n, blocks);
    } else {
        float* acc = (float*)d_ws;
        hipMemsetAsync(d_ws, 0, accBytes, stream);
        gather_sum_kernel<<<512, 256, 0, stream>>>(idx, memb, pre, acc, n);
        finish_kernel<<<256, 256, 0, stream>>>(acc, W, bias, out, (float)n);
    }
}

// Round 7
// 48.861 us; speedup vs baseline: 2.5954x; 2.5954x over previous
//
#include <hip/hip_runtime.h>

// out[c] = sum_i pre[idx_i][c] + dot(W[c,:], sum_i memb[idx_i]) + N*bias[c]
//
// Histogram formulation: counts[v] = multiplicity of row v (~39% of the 200k
// vocab rows touched by 100k uniform draws); one monotone weighted scan reads
// each unique row ONCE from each table (~158 MB logical; rocprof shows only
// ~79 MB from HBM -- L3 retains about half across replays).
//
// R7 = exact R5 structure (proven 49.7us: int32 counts, STANDALONE scan
// kernel, separate finish -- R6's fused kernel collapsed to VGPR=20 and
// serialized all loads), with ONE change: inner loop 4-wide -> 8-wide.
// All 8 (row,weight) extractions are register-only (ffs/shfl) and precede
// the 8 independent 1KB row loads, which precede the 8 FMAs.
//
// d_ws layout: [counts: V int32][acc: NCOPY*512 f32]

typedef float f4 __attribute__((ext_vector_type(4)));

#define NCOPY 16

__global__ __launch_bounds__(256) void hist_kernel(
    const int* __restrict__ idx, int* __restrict__ counts, int n)
{
    int i = blockIdx.x * blockDim.x + threadIdx.x;
    const int stride = gridDim.x * blockDim.x;
    for (; i < n; i += stride) atomicAdd(&counts[idx[i]], 1);
}

__global__ __launch_bounds__(256) void scan_kernel(
    const int* __restrict__ counts,
    const float* __restrict__ memb,   // [V,256]
    const float* __restrict__ pre,    // [V,256]
    float* __restrict__ acc,          // [NCOPY][512]
    int vocab)
{
    const int lane = threadIdx.x & 63;
    const int wid  = (blockIdx.x * blockDim.x + threadIdx.x) >> 6;
    const int tab  = wid & 1;                 // 0 -> memb, 1 -> pre
    const int base = (wid >> 1) * 64;         // 64-row window per wave pair

    f4 a4 = {0.f, 0.f, 0.f, 0.f};

    if (base < vocab) {
        int c = 0;
        if (base + lane < vocab) c = counts[base + lane];   // coalesced
        const float cf = (float)c;
        unsigned long long m = __ballot(c != 0);

        const float* tbl = tab ? pre : memb;
        const f4* rows = reinterpret_cast<const f4*>(tbl) + (size_t)base * 64 + lane;

        // 8 surviving rows per iteration. Control is wave-uniform (ballot
        // mask); extraction is register-only ffs/shfl; then 8 independent
        // 1KB loads; then 8 FMAs. Tail pads with (k0, weight 0) -> L1 hit.
        while (m) {
            int   k[8];
            float w[8];
            k[0] = __ffsll(m) - 1; m &= m - 1;
            w[0] = __shfl(cf, k[0], 64);
            #pragma unroll
            for (int j = 1; j < 8; ++j) {
                if (m) { k[j] = __ffsll(m) - 1; m &= m - 1; w[j] = __shfl(cf, k[j], 64); }
                else   { k[j] = k[0];           w[j] = 0.f; }
            }

            f4 a[8];
            #pragma unroll
            for (int j = 0; j < 8; ++j) a[j] = rows[(size_t)k[j] * 64];

            #pragma unroll
            for (int j = 0; j < 8; ++j) a4 += a[j] * w[j];
        }
    }

    // Block reduction: lane l owns channels [4l,4l+4); even waves -> S,
    // odd waves -> P.
    __shared__ float sAcc[2][256];
    sAcc[0][threadIdx.x] = 0.f;
    sAcc[1][threadIdx.x] = 0.f;
    __syncthreads();

    const int ch = lane * 4;
    atomicAdd(&sAcc[tab][ch + 0], a4.x);
    atomicAdd(&sAcc[tab][ch + 1], a4.y);
    atomicAdd(&sAcc[tab][ch + 2], a4.z);
    atomicAdd(&sAcc[tab][ch + 3], a4.w);
    __syncthreads();

    float* myacc = acc + (size_t)(blockIdx.x & (NCOPY - 1)) * 512;
    atomicAdd(&myacc[threadIdx.x],       sAcc[0][threadIdx.x]);
    atomicAdd(&myacc[256 + threadIdx.x], sAcc[1][threadIdx.x]);
}

__global__ __launch_bounds__(256) void finish_kernel(
    const float* __restrict__ acc,    // [NCOPY][512]
    const float* __restrict__ W,      // [256,256] row-major
    const float* __restrict__ bias,
    float* __restrict__ out,          // [256]
    float nf)
{
    const int c = blockIdx.x;
    const int t = threadIdx.x;

    float s_t = 0.f;
    #pragma unroll
    for (int cp = 0; cp < NCOPY; ++cp) s_t += acc[cp * 512 + t];

    float v = W[(size_t)c * 256 + t] * s_t;
    for (int off = 32; off > 0; off >>= 1)
        v += __shfl_down(v, off, 64);

    __shared__ float part[4];
    if ((t & 63) == 0) part[t >> 6] = v;
    __syncthreads();

    if (t == 0) {
        float p_c = 0.f;
        #pragma unroll
        for (int cp = 0; cp < NCOPY; ++cp) p_c += acc[cp * 512 + 256 + c];
        out[c] = (part[0] + part[1] + part[2] + part[3]) + p_c + nf * bias[c];
    }
}

// Fallback (ws too small): direct strided gather into acc copies.
__global__ __launch_bounds__(256) void gather_sum_kernel(
    const int* __restrict__ idx,
    const float* __restrict__ memb,
    const float* __restrict__ pre,
    float* __restrict__ acc,
    int n)
{
    const int lane = threadIdx.x & 63;
    const int wave = threadIdx.x >> 6;
    const int globalWave = blockIdx.x * 4 + wave;
    const int totalWaves = gridDim.x * 4;

    f4 accS = {0.f,0.f,0.f,0.f};
    f4 accP = {0.f,0.f,0.f,0.f};

    for (int i = globalWave; i < n; i += totalWaves) {
        const int r = idx[i];
        const f4 a = reinterpret_cast<const f4*>(memb + (size_t)r * 256)[lane];
        const f4 b = reinterpret_cast<const f4*>(pre  + (size_t)r * 256)[lane];
        accS += a; accP += b;
    }

    __shared__ float sS[256];
    __shared__ float sP[256];
    sS[threadIdx.x] = 0.f;
    sP[threadIdx.x] = 0.f;
    __syncthreads();
    const int ch = lane * 4;
    atomicAdd(&sS[ch + 0], accS.x); atomicAdd(&sS[ch + 1], accS.y);
    atomicAdd(&sS[ch + 2], accS.z); atomicAdd(&sS[ch + 3], accS.w);
    atomicAdd(&sP[ch + 0], accP.x); atomicAdd(&sP[ch + 1], accP.y);
    atomicAdd(&sP[ch + 2], accP.z); atomicAdd(&sP[ch + 3], accP.w);
    __syncthreads();
    float* myacc = acc + (size_t)(blockIdx.x & (NCOPY - 1)) * 512;
    atomicAdd(&myacc[threadIdx.x],       sS[threadIdx.x]);
    atomicAdd(&myacc[256 + threadIdx.x], sP[threadIdx.x]);
}

extern "C" void kernel_launch(void* const* d_in, const int* in_sizes, int n_in,
                              void* d_out, int out_size, void* d_ws, size_t ws_size,
                              hipStream_t stream)
{
    const int*   idx  = (const int*)d_in[0];     // medicine_it      [N]
    const float* memb = (const float*)d_in[1];   // m_embeddings     [V,256]
    const float* pre  = (const float*)d_in[2];   // pretrained_weight[V,256]
    const float* W    = (const float*)d_in[3];   // W                [256,256]
    const float* bias = (const float*)d_in[4];   // bias             [256]
    float* out = (float*)d_out;

    const int n     = in_sizes[0];
    const int vocab = in_sizes[1] / 256;

    const size_t countsBytes = (size_t)vocab * sizeof(int);
    const size_t accBytes    = (size_t)NCOPY * 512 * sizeof(float);

    if (ws_size >= countsBytes + accBytes) {
        int*   counts = (int*)d_ws;
        float* acc    = (float*)((char*)d_ws + countsBytes);

        hipMemsetAsync(d_ws, 0, countsBytes + accBytes, stream);
        hist_kernel<<<400, 256, 0, stream>>>(idx, counts, n);

        const int waves  = 2 * ((vocab + 63) / 64);          // 6250
        const int blocks = (waves + 3) / 4;                  // 1563
        scan_kernel<<<blocks, 256, 0, stream>>>(counts, memb, pre, acc, vocab);
        finish_kernel<<<256, 256, 0, stream>>>(acc, W, bias, out, (float)n);
    } else {
        float* acc = (float*)d_ws;
        hipMemsetAsync(d_ws, 0, accBytes, stream);
        gather_sum_kernel<<<512, 256, 0, stream>>>(idx, memb, pre, acc, n);
        finish_kernel<<<256, 256, 0, stream>>>(acc, W, bias, out, (float)n);
    }
}